// Round 3
// baseline (163.246 us; speedup 1.0000x reference)
//
#include <hip/hip_runtime.h>
#include <hip/hip_cooperative_groups.h>
#include <cstddef>
#include <cstdint>

namespace cg = cooperative_groups;

// Problem constants (match reference setup_inputs)
#define HH    128
#define WW    128
#define CC    392           // K*K*8 = 49*8
#define NPIX  (HH*WW)       // 16384
#define NROI  2048
#define PSK   7
#define NBIN  49
#define LAMDA 0.1f

// MFMA conv layout constants
#define CPAD      448       // input channels padded to 7*64
#define HPAD      130       // 128 + 1px zero halo each side
#define SEGSTRIDE (9*CPAD)  // 4032 elems per co row in Bth
#define BKK       64        // K-chunk per substep
#define NSS       21        // supersteps: 3 dy x 7 k-chunks
#define NZ        63        // substeps: NSS x 3 dx

// LDS: A panel 136 rows (130 used) x 64 halves, B tile 128 x 64 halves, x2 dbuf
#define ATH     (136*BKK)     // 8704 halves = 17408 B
#define BTH     (128*BKK)     // 8192 halves = 16384 B

// mega-kernel geometry: 512 blocks x 512 threads (8 waves), 2 blocks/CU
#define NBLK    512
#define NTHR    512
#define GSTRIDE (NBLK*NTHR)
#define FTOT    (HPAD*HPAD*(CPAD/8))    // 946400 feature half8-groups
#define WTILES  (9*14*13)               // 1638 weight 32x32 tiles
#define POOL8   (NROI*NBIN*8)           // 802816 = 3136*256 exactly

typedef _Float16 half8   __attribute__((ext_vector_type(8)));
typedef _Float16 half4v  __attribute__((ext_vector_type(4)));
typedef _Float16 half2v  __attribute__((ext_vector_type(2)));
typedef float    floatx4 __attribute__((ext_vector_type(4)));

// ---------------------------------------------------------------------------
// async global->LDS 16B (dest = wave-uniform base + lane*16)
// ---------------------------------------------------------------------------
__device__ __forceinline__ void async_ld16(const _Float16* g, _Float16* l) {
  __builtin_amdgcn_global_load_lds((const __attribute__((address_space(1))) void*)g,
                                   (__attribute__((address_space(3))) void*)l,
                                   16, 0, 0);
}

// one barrier per substep: drain this wave's DMA, then block barrier
__device__ __forceinline__ void sync_step() {
  asm volatile("s_waitcnt vmcnt(0)" ::: "memory");
  __builtin_amdgcn_s_barrier();
  asm volatile("" ::: "memory");
}

// ---------------------------------------------------------------------------
// Prep 1: features fp32 [128,128,392] -> f16 [130,130,448] halo+pad (grid-stride)
// ---------------------------------------------------------------------------
__device__ __forceinline__ void prep_features(const float* __restrict__ F,
                                              _Float16* __restrict__ Fh,
                                              int gtid, int stride) {
  for (int idx = gtid; idx < FTOT; idx += stride) {
    const int p   = idx / (CPAD / 8);
    const int cgi = idx - p * (CPAD / 8);
    const int c   = cgi * 8;
    const int py  = p / HPAD;
    const int px  = p - py * HPAD;
    half8 h;
#pragma unroll
    for (int i = 0; i < 8; ++i) h[i] = (_Float16)0.f;
    if (py >= 1 && py <= HH && px >= 1 && px <= WW && c < CC) {
      const float* src = F + ((size_t)(py - 1) * WW + (px - 1)) * CC + c;
      const float4 v0 = *(const float4*)src;
      const float4 v1 = *(const float4*)(src + 4);
      h[0] = (_Float16)v0.x; h[1] = (_Float16)v0.y;
      h[2] = (_Float16)v0.z; h[3] = (_Float16)v0.w;
      h[4] = (_Float16)v1.x; h[5] = (_Float16)v1.y;
      h[6] = (_Float16)v1.z; h[7] = (_Float16)v1.w;
    }
    *(half8*)(Fh + (size_t)p * CPAD + c) = h;
  }
}

// ---------------------------------------------------------------------------
// Prep 2: weights fp32 [9,392,392] (seg,ci,co) -> f16 Bth[co][seg][ci'] via
// 32x32 LDS tile transpose; ci padded to 448. Thread-count agnostic.
// ---------------------------------------------------------------------------
__device__ __forceinline__ void prep_weights(const float* __restrict__ Wt,
                                             _Float16* __restrict__ Bth,
                                             float (*tile)[33],
                                             int bid, int t, int bdim, int nblocks) {
  for (int tl = bid; tl < WTILES; tl += nblocks) {
    const int seg = tl / (14 * 13);
    const int rem = tl - seg * (14 * 13);
    const int cit = rem / 13;         // ci tile 0..13
    const int cot = rem - cit * 13;   // co tile 0..12
    const int ci0 = cit * 32, co0 = cot * 32;
    __syncthreads();                  // protect tile reuse across iterations
    for (int idx = t; idx < 1024; idx += bdim) {
      const int lr = idx >> 5;        // local ci
      const int lc = idx & 31;        // local co (fast -> coalesced read)
      const int ci = ci0 + lr, co = co0 + lc;
      float v = 0.f;
      if (ci < CC && co < CC) v = Wt[((size_t)seg * CC + ci) * CC + co];
      tile[lr][lc] = v;
    }
    __syncthreads();
    for (int idx = t; idx < 1024; idx += bdim) {
      const int lr = idx >> 5;        // local co
      const int lc = idx & 31;        // local ci (fast -> coalesced write)
      Bth[(size_t)(co0 + lr) * SEGSTRIDE + seg * CPAD + ci0 + lc] = (_Float16)tile[lc][lr];
    }
  }
}

// ---------------------------------------------------------------------------
// Staging (8-wave): A panel = 130 Fh pixels of row fy at k-chunk cb into
// As[136][64] with the XOR swizzle (row r's logical 16B-group g at phys
// g^(r&7)). Wave w stages rows 16w..16w+15 (2 insts); wave 7 adds 128..135
// (clamped to px 129). B tile: wave w stages co rows 16w..16w+15.
// ---------------------------------------------------------------------------
__device__ __forceinline__ void stage_a8(const _Float16* __restrict__ Fh,
                                         int fy, int cb, _Float16* As, int t) {
  const int L = t & 63, w = t >> 6;
  const int srow = L >> 3;
  const int kofs = ((L & 7) ^ srow) * 8;   // pre-swizzled source k-group
  const _Float16* gA = Fh + (size_t)fy * HPAD * CPAD + kofs + cb;
#pragma unroll
  for (int j = 0; j < 2; ++j) {
    const int r = w * 16 + j * 8;
    async_ld16(gA + (size_t)(r + srow) * CPAD, &As[r * BKK]);
  }
  if (w == 7) {
    const int rr = 128 + srow;
    const int rp = (rr <= 129) ? rr : 129;  // rows 130..135 never read
    async_ld16(gA + (size_t)rp * CPAD, &As[128 * BKK]);
  }
}

__device__ __forceinline__ void stage_b8(const _Float16* __restrict__ Bth,
                                         int col0, int seg, int cb, _Float16* Bs, int t) {
  const int L = t & 63, w = t >> 6;
  const int srow = L >> 3;
  const int kofs = ((L & 7) ^ srow) * 8;
  const _Float16* gB = Bth + (size_t)(col0 + w * 16 + srow) * SEGSTRIDE + seg * CPAD + kofs + cb;
#pragma unroll
  for (int j = 0; j < 2; ++j)
    async_ld16(gB + (size_t)(j * 8) * SEGSTRIDE, &Bs[(w * 16 + j * 8) * BKK]);
}

__device__ __forceinline__ void stage_b_thin8(const _Float16* __restrict__ Bth,
                                              int seg, int cb, _Float16* Bs, int t) {
  const int L = t & 63, w = t >> 6;
  if (w >= 2) return;                      // 16 rows = 2 insts, waves 0-1
  const int srow = L >> 3;
  const int kofs = ((L & 7) ^ srow) * 8;
  const _Float16* gB = Bth + (size_t)(384 + w * 8 + srow) * SEGSTRIDE + seg * CPAD + kofs + cb;
  async_ld16(gB, &Bs[(w * 8) * BKK]);
}

// ---------------------------------------------------------------------------
// Fat conv tile: 128M x 128N output, full K (no split), 8 waves 2Mx4N,
// wave 64x32 = 4x2 mfma_f32_16x16x32_f16 x2 per substep. FULL double buffer
// (A panel + B tile): stage(z+1) issued BEFORE compute(z); ONE vmcnt(0)+
// barrier per substep, so staging latency hides under ds_read+MFMA.
// Superstep = (dy, k-chunk): A staged once per superstep, dx shifts read rows.
// ---------------------------------------------------------------------------
__device__ __forceinline__ void conv_fat(const _Float16* __restrict__ Fh,
                                         const _Float16* __restrict__ Bth,
                                         _Float16* __restrict__ OM,
                                         _Float16* As, _Float16* Bs,
                                         int row0, int col0, int t) {
  const int L = t & 63;
  const int w = t >> 6;
  const int ya = row0 >> 7;                // image y for this M-tile
  const int fr = L & 15;
  const int quad = L >> 4;
  const int wm = (w >> 2) * 64;
  const int wn = (w & 3) * 32;

  floatx4 acc[4][2];
#pragma unroll
  for (int i = 0; i < 4; ++i)
#pragma unroll
    for (int j = 0; j < 2; ++j) {
      floatx4 z = {0.f, 0.f, 0.f, 0.f};
      acc[i][j] = z;
    }

  // prologue: fill buffers 0 with (s=0: dy=-1, k-chunk 0, dx=-1)
  stage_a8(Fh, ya, 0, As, t);
  stage_b8(Bth, col0, 0, 0, Bs, t);
  sync_step();

  int pa = 0, pb = 0;
  for (int z = 0; z < NZ; ++z) {
    const int dxs = z - (z / 3) * 3;
    if (z + 1 < NZ) {                      // issue next substep's staging first
      const int z2 = z + 1;
      const int s2 = z2 / 3;
      const int dxs2 = z2 - s2 * 3;
      const int dyi2 = s2 / 7;
      const int it2 = s2 - dyi2 * 7;
      const int cb2 = it2 * BKK;
      if (dxs2 == 0) stage_a8(Fh, ya + dyi2, cb2, As + (pa ^ 1) * ATH, t);
      stage_b8(Bth, col0, dyi2 * 3 + dxs2, cb2, Bs + (pb ^ 1) * BTH, t);
    }
    const _Float16* Ab = As + pa * ATH;
    const _Float16* Bb = Bs + pb * BTH;
#pragma unroll
    for (int kh = 0; kh < 2; ++kh) {
      const int q = kh * 4 + quad;
      half8 av[4], bv[2];
#pragma unroll
      for (int mt = 0; mt < 4; ++mt) {
        const int row = wm + mt * 16 + fr + dxs;   // A row = out pixel + dx + 1
        av[mt] = *(const half8*)(&Ab[row * BKK + ((q ^ (row & 7)) * 8)]);
      }
#pragma unroll
      for (int nt = 0; nt < 2; ++nt) {
        const int rb = wn + nt * 16 + fr;
        bv[nt] = *(const half8*)(&Bb[rb * BKK + ((q ^ (fr & 7)) * 8)]);
      }
#pragma unroll
      for (int mt = 0; mt < 4; ++mt)
#pragma unroll
        for (int nt = 0; nt < 2; ++nt)
          acc[mt][nt] = __builtin_amdgcn_mfma_f32_16x16x32_f16(av[mt], bv[nt], acc[mt][nt], 0, 0, 0);
    }
    sync_step();                           // drains stage(z+1); frees cur bufs
    if (dxs == 2) pa ^= 1;
    pb ^= 1;
  }

  // epilogue: C/D mapping col=lane&15, row=(lane>>4)*4+reg (cols all < 384)
#pragma unroll
  for (int mt = 0; mt < 4; ++mt) {
    const int rbase = row0 + wm + mt * 16 + quad * 4;
#pragma unroll
    for (int nt = 0; nt < 2; ++nt) {
      const int col = col0 + wn + nt * 16 + fr;
#pragma unroll
      for (int r = 0; r < 4; ++r)
        OM[(size_t)(rbase + r) * CC + col] = (_Float16)acc[mt][nt][r];
    }
  }
}

// ---------------------------------------------------------------------------
// Thin conv tile: 128M x 16N (cols 384..399, real 384..391), full K.
// 8 waves stacked in M (wave 16M x 16N, acc 1). Same dbuf schedule.
// ---------------------------------------------------------------------------
__device__ __forceinline__ void conv_thin(const _Float16* __restrict__ Fh,
                                          const _Float16* __restrict__ Bth,
                                          _Float16* __restrict__ OM,
                                          _Float16* As, _Float16* Bs,
                                          int row0, int t) {
  const int L = t & 63;
  const int w = t >> 6;
  const int ya = row0 >> 7;
  const int fr = L & 15;
  const int quad = L >> 4;
  const int wm = w * 16;

  floatx4 acc = {0.f, 0.f, 0.f, 0.f};

  stage_a8(Fh, ya, 0, As, t);
  stage_b_thin8(Bth, 0, 0, Bs, t);
  sync_step();

  int pa = 0, pb = 0;
  for (int z = 0; z < NZ; ++z) {
    const int dxs = z - (z / 3) * 3;
    if (z + 1 < NZ) {
      const int z2 = z + 1;
      const int s2 = z2 / 3;
      const int dxs2 = z2 - s2 * 3;
      const int dyi2 = s2 / 7;
      const int it2 = s2 - dyi2 * 7;
      const int cb2 = it2 * BKK;
      if (dxs2 == 0) stage_a8(Fh, ya + dyi2, cb2, As + (pa ^ 1) * ATH, t);
      stage_b_thin8(Bth, dyi2 * 3 + dxs2, cb2, Bs + (pb ^ 1) * BTH, t);
    }
    const _Float16* Ab = As + pa * ATH;
    const _Float16* Bb = Bs + pb * BTH;
#pragma unroll
    for (int kh = 0; kh < 2; ++kh) {
      const int q = kh * 4 + quad;
      const int row = wm + fr + dxs;
      const half8 av = *(const half8*)(&Ab[row * BKK + ((q ^ (row & 7)) * 8)]);
      const half8 bv = *(const half8*)(&Bb[fr * BKK + ((q ^ (fr & 7)) * 8)]);
      acc = __builtin_amdgcn_mfma_f32_16x16x32_f16(av, bv, acc, 0, 0, 0);
    }
    sync_step();
    if (dxs == 2) pa ^= 1;
    pb ^= 1;
  }

  const int rbase = row0 + wm + quad * 4;
  const int col = 384 + fr;
  if (col < CC) {
#pragma unroll
    for (int r = 0; r < 4; ++r)
      OM[(size_t)(rbase + r) * CC + col] = (_Float16)acc[r];
  }
}

// ---------------------------------------------------------------------------
// Conv block decode: bid in [0,512). x = bid&127 (M-tile = image row),
// cg = bid>>7: 0..2 -> fat col tile, 3 -> thin.
// ---------------------------------------------------------------------------
__device__ __forceinline__ void conv_dispatch(const _Float16* Fh, const _Float16* Bth,
                                              _Float16* OM,
                                              _Float16* As, _Float16* Bs,
                                              int bid, int t) {
  const int x = bid & 127;
  const int cg = bid >> 7;
  if (cg < 3)
    conv_fat(Fh, Bth, OM, As, Bs, x * 128, cg * 128, t);
  else
    conv_thin(Fh, Bth, OM, As, Bs, x * 128, t);
}

// ---------------------------------------------------------------------------
// Pool (8 lanes per (roi,bin)): lane j in 0..7.
// Stage 1: corner c=j&3, channel-half hf=j>>2 -> ONE half4 (8B) load each;
// butterfly xor 1,2 sums corners; xor 4 EXCHANGES halves (no split-K now) so
// every lane can select channels 2g, 2g+1. Stage 2 unchanged.
// ---------------------------------------------------------------------------
__device__ __forceinline__ void bilin_setup(float y, float x,
                                            int& iy0, int& iy1, int& ix0, int& ix1,
                                            float& w00, float& w01, float& w10, float& w11) {
  const float y0f = floorf(y), x0f = floorf(x);
  const float wy = y - y0f, wx = x - x0f;   // unclamped, matches reference
  const int a = (int)y0f, b = (int)x0f;
  iy0 = min(max(a, 0), HH - 1);
  iy1 = min(max(a + 1, 0), HH - 1);
  ix0 = min(max(b, 0), WW - 1);
  ix1 = min(max(b + 1, 0), WW - 1);
  w00 = (1.f - wy) * (1.f - wx);
  w01 = (1.f - wy) * wx;
  w10 = wy * (1.f - wx);
  w11 = wy * wx;
}

__device__ __forceinline__ void pool_item8(const _Float16* __restrict__ Fh,
                                           const float* __restrict__ R,
                                           const _Float16* __restrict__ OM,
                                           float* __restrict__ out, int tid) {
  const int j  = tid & 7;          // lane role within (roi,bin)
  const int nb = tid >> 3;
  const int n  = nb / NBIN;
  const int b  = nb - n * NBIN;
  const int bi = b / PSK;
  const int bj = b - bi * PSK;

  const float rx1 = R[n * 5 + 1], ry1 = R[n * 5 + 2];
  const float rx2 = R[n * 5 + 3], ry2 = R[n * 5 + 4];
  const float x1 = rx1 * (1.f / 16.f);
  const float y1 = ry1 * (1.f / 16.f);
  const float x2 = (rx2 + 1.f) * (1.f / 16.f);
  const float y2 = (ry2 + 1.f) * (1.f / 16.f);
  const float bw = (x2 - x1) * (1.f / 7.f);
  const float bh = (y2 - y1) * (1.f / 7.f);
  const float cx = x1 + ((float)bj + 0.5f) * bw;
  const float cy = y1 + ((float)bi + 0.5f) * bh;
  const float sxs = (rx2 - rx1 + 1.f) * (LAMDA / 16.f);
  const float sys = (ry2 - ry1 + 1.f) * (LAMDA / 16.f);

  // ---- stage 1: lane = (corner j&3, channel-half j>>2); one half4 load ----
  int iy0, iy1, ix0, ix1;
  float w00, w01, w10, w11;
  bilin_setup(cy, cx, iy0, iy1, ix0, ix1, w00, w01, w10, w11);

  const int c = j & 3;
  const int hf = j >> 2;
  const int cyi = (c >> 1) ? iy1 : iy0;
  const int cxi = (c & 1) ? ix1 : ix0;
  const float wq = (c == 0) ? w00 : (c == 1) ? w01 : (c == 2) ? w10 : w11;

  const size_t base = (size_t)(cyi * WW + cxi) * CC + (size_t)b * 8 + hf * 4;
  const half4v hv = *(const half4v*)(OM + base);

  float o4[4];
#pragma unroll
  for (int i = 0; i < 4; ++i) o4[i] = wq * (float)hv[i];
#pragma unroll
  for (int i = 0; i < 4; ++i) o4[i] += __shfl_xor(o4[i], 1);
#pragma unroll
  for (int i = 0; i < 4; ++i) o4[i] += __shfl_xor(o4[i], 2);
  float oth[4];
#pragma unroll
  for (int i = 0; i < 4; ++i) oth[i] = __shfl_xor(o4[i], 4);

  // lane holds channels [4hf..4hf+3] in o4, the other half in oth
  const int g = j & 3;
  const int i0 = (g & 1) * 2;              // (2g)&3
  const bool sel = ((g >> 1) == hf);
  const float ox = sel ? o4[i0]     : oth[i0];       // channel 2g
  const float oy = sel ? o4[i0 + 1] : oth[i0 + 1];   // channel 2g+1
  const float sx = cx + ox * sxs;
  const float sy = cy + oy * sys;

  // ---- stage 2: lane = (group g, y-half j>>2); two half2 loads ----
  int jy0, jy1, jx0, jx1;
  float u00, u01, u10, u11;
  bilin_setup(sy, sx, jy0, jy1, jx0, jx1, u00, u01, u10, u11);

  const int  yh = j >> 2;
  const int  jy = yh ? jy1 : jy0;
  const float ua = yh ? u10 : u00;   // weight at (jy, jx0)
  const float ub = yh ? u11 : u01;   // weight at (jy, jx1)

  const size_t c0 = (size_t)b * 8 + 2 * g;
  const half2v qa = *(const half2v*)(Fh + ((size_t)(jy + 1) * HPAD + (jx0 + 1)) * CPAD + c0);
  const half2v qb = *(const half2v*)(Fh + ((size_t)(jy + 1) * HPAD + (jx1 + 1)) * CPAD + c0);

  float v0 = ua * (float)qa[0] + ub * (float)qb[0];
  float v1 = ua * (float)qa[1] + ub * (float)qb[1];
  v0 += __shfl_xor(v0, 4);
  v1 += __shfl_xor(v1, 4);

  // lane j<4 writes channel 2g, lane j>=4 writes channel 2g+1 (one store each)
  const float vout = yh ? v1 : v0;
  out[((size_t)n * 8 + 2 * g + yh) * NBIN + b] = vout;
}

// ---------------------------------------------------------------------------
// Cooperative kernel: prep -> grid.sync -> full-K conv (512 blocks x 512 thr).
// ---------------------------------------------------------------------------
__global__ __launch_bounds__(NTHR, 4)
void mega_kernel(const float* __restrict__ F, const float* __restrict__ Wt,
                 _Float16* __restrict__ OM,
                 _Float16* __restrict__ Fh, _Float16* __restrict__ Bth) {
  __shared__ __align__(16) _Float16 smem[2 * ATH + 2 * BTH];  // 66 KB -> 2 blocks/CU
  const int bid = blockIdx.x;
  const int t = threadIdx.x;
  cg::grid_group grid = cg::this_grid();

  prep_features(F, Fh, bid * NTHR + t, GSTRIDE);
  prep_weights(Wt, Bth, (float(*)[33])smem, bid, t, NTHR, NBLK);

  __threadfence();
  grid.sync();

  conv_dispatch(Fh, Bth, OM, smem, smem + 2 * ATH, bid, t);
}

__global__ __launch_bounds__(256)
void pool_kernel(const _Float16* __restrict__ Fh, const float* __restrict__ R,
                 const _Float16* __restrict__ OM, float* __restrict__ out) {
  pool_item8(Fh, R, OM, out, blockIdx.x * 256 + threadIdx.x);
}

// ---------------------------------------------------------------------------
// Non-coop fallback (same device code, separate launches)
// ---------------------------------------------------------------------------
__global__ __launch_bounds__(256)
void prep_kernel_sa(const float* __restrict__ F, const float* __restrict__ Wt,
                    _Float16* __restrict__ Fh, _Float16* __restrict__ Bth) {
  __shared__ float tile[32][33];
  prep_features(F, Fh, blockIdx.x * 256 + threadIdx.x, gridDim.x * 256);
  prep_weights(Wt, Bth, tile, blockIdx.x, threadIdx.x, 256, gridDim.x);
}

__global__ __launch_bounds__(NTHR, 4)
void conv_kernel_sa(const _Float16* __restrict__ Fh, const _Float16* __restrict__ Bth,
                    _Float16* __restrict__ OM) {
  __shared__ __align__(16) _Float16 smem[2 * ATH + 2 * BTH];
  conv_dispatch(Fh, Bth, OM, smem, smem + 2 * ATH, blockIdx.x, threadIdx.x);
}

extern "C" void kernel_launch(void* const* d_in, const int* in_sizes, int n_in,
                              void* d_out, int out_size, void* d_ws, size_t ws_size,
                              hipStream_t stream) {
  const float* F  = (const float*)d_in[0];   // features [1,128,128,392] fp32
  const float* R  = (const float*)d_in[1];   // rois [2048,5] fp32
  const float* Wt = (const float*)d_in[2];   // conv_w [3,3,392,392] fp32
  float* out = (float*)d_out;                // [2048,8,7,7] fp32

  const size_t omBytes  = (size_t)NPIX * CC * sizeof(_Float16);            // 12.85 MB
  const size_t fhBytes  = (size_t)HPAD * HPAD * CPAD * sizeof(_Float16);   // 15.14 MB
  // Bth: 416-ish rows x 4032 x 2B = 3.35 MB; total ~31.3 MB

  _Float16* OM  = (_Float16*)d_ws;
  _Float16* Fh  = (_Float16*)((char*)d_ws + omBytes);
  _Float16* Bth = (_Float16*)((char*)d_ws + omBytes + fhBytes);

  int maxBlk = 0;
  hipError_t qerr = hipOccupancyMaxActiveBlocksPerMultiprocessor(&maxBlk, mega_kernel, NTHR, 0);
  bool coopOk = (qerr == hipSuccess && maxBlk >= 2);

  if (coopOk) {
    void* args[] = {(void*)&F, (void*)&Wt, (void*)&OM, (void*)&Fh, (void*)&Bth};
    hipError_t err = hipLaunchCooperativeKernel((const void*)mega_kernel,
                                                dim3(NBLK), dim3(NTHR),
                                                args, 0, stream);
    if (err != hipSuccess) {
      (void)hipGetLastError();
      coopOk = false;
    }
  }
  if (!coopOk) {
    prep_kernel_sa<<<2048, 256, 0, stream>>>(F, Wt, Fh, Bth);
    conv_kernel_sa<<<NBLK, NTHR, 0, stream>>>(Fh, Bth, OM);
  }

  pool_kernel<<<POOL8 / 256, 256, 0, stream>>>(Fh, R, OM, out);
}